// Round 3
// baseline (173.064 us; speedup 1.0000x reference)
//
#include <hip/hip_runtime.h>

// InformPooling, two-pass chunk-sum scheme, all 16B/lane (float4) memory ops.
//   value0 [8,16384,128] r=1.0 ; value1 [8,8192,128] r=0.5 ; value2 [8,4096,256] r=0.25
//   start/duration [8,512]; out [8,512,512] f32 (channels concat 128|128|256).
//
// Pass 1 (chunk_sum): stream v once, write sums of kC=8 consecutive rows into d_ws.
//   S0 [8][2048][128], S1 [8][1024][128], S2 [8][512][256] -> 16.8 MB (LLC-hot).
//   128-ch pools: half-wave (32 lanes x float4) per chunk, 2 chunks per wave ->
//   every load = 16B/lane, store = contiguous 1024B per wave, no shuffles.
// Pass 2 (gather): per (b,n,pool) wave. 128-ch pools: halves split chunks/rows by
//   parity, combine once via shfl_xor(32). Pool2: row = 64 x float4 exactly.
// R1 evidence: float2 (8B/lane) capped streaming at ~3 TB/s logical; float4 copy
// ceiling is 6.3 TB/s (m13).

constexpr int   kB   = 8;
constexpr int   kN   = 512;
constexpr float kEps = 1e-3f;
constexpr int   kC   = 8;  // chunk rows

// float offsets into ws
constexpr size_t S0_OFF = 0;                       // 8*2048*128
constexpr size_t S1_OFF = (size_t)8 * 2048 * 128;  // + 8*1024*128
constexpr size_t S2_OFF = S1_OFF + (size_t)8 * 1024 * 128;

static __device__ __forceinline__ float4 f4add(float4 a, float4 b) {
    a.x += b.x; a.y += b.y; a.z += b.z; a.w += b.w; return a;
}

__global__ __launch_bounds__(256) void chunk_sum_kernel(
    const float* __restrict__ v0, const float* __restrict__ v1,
    const float* __restrict__ v2, float* __restrict__ ws)
{
    const int w    = (blockIdx.x * 256 + threadIdx.x) >> 6;  // global wave id [0,14336)
    const int lane = threadIdx.x & 63;
    const int half = lane >> 5;   // which chunk of the pair (128-ch pools)
    const int q    = lane & 31;   // float4 channel group (128-ch pools)

    if (w < 8192) {                        // pool0: 8 b x 1024 chunk-pairs
        const int b = w >> 10, pc = w & 1023;
        const int c = pc * 2 + half;       // this half-wave's chunk
        const float4* p = (const float4*)(v0 + ((size_t)b * 16384 + (size_t)c * kC) * 128) + q;
        float4 a0 = make_float4(0, 0, 0, 0), a1 = make_float4(0, 0, 0, 0);
#pragma unroll
        for (int i = 0; i < kC; i += 2) {  // row stride = 32 float4
            a0 = f4add(a0, p[(size_t)i * 32]);
            a1 = f4add(a1, p[(size_t)(i + 1) * 32]);
        }
        ((float4*)(ws + S0_OFF + ((size_t)b * 2048 + c) * 128))[q] = f4add(a0, a1);
    } else if (w < 12288) {                // pool1: 8 b x 512 chunk-pairs
        const int idx = w - 8192;
        const int b = idx >> 9, pc = idx & 511;
        const int c = pc * 2 + half;
        const float4* p = (const float4*)(v1 + ((size_t)b * 8192 + (size_t)c * kC) * 128) + q;
        float4 a0 = make_float4(0, 0, 0, 0), a1 = make_float4(0, 0, 0, 0);
#pragma unroll
        for (int i = 0; i < kC; i += 2) {
            a0 = f4add(a0, p[(size_t)i * 32]);
            a1 = f4add(a1, p[(size_t)(i + 1) * 32]);
        }
        ((float4*)(ws + S1_OFF + ((size_t)b * 1024 + c) * 128))[q] = f4add(a0, a1);
    } else if (w < 14336) {                // pool2: 8 b x 256 chunk-pairs, 256 ch
        const int idx = w - 12288;
        const int b = idx >> 8, pc = idx & 255;
        const int c0 = pc * 2;
        const float4* p = (const float4*)(v2 + ((size_t)b * 4096 + (size_t)c0 * kC) * 256) + lane;
        float4 a0 = make_float4(0, 0, 0, 0), a1 = make_float4(0, 0, 0, 0);
        float4 b0 = make_float4(0, 0, 0, 0), b1 = make_float4(0, 0, 0, 0);
#pragma unroll
        for (int i = 0; i < kC; i += 2) {  // row stride = 64 float4; rows 8..15 = chunk c0+1
            a0 = f4add(a0, p[(size_t)i * 64]);
            a1 = f4add(a1, p[(size_t)(i + 1) * 64]);
            b0 = f4add(b0, p[(size_t)(i + 8) * 64]);
            b1 = f4add(b1, p[(size_t)(i + 9) * 64]);
        }
        float4* sp = (float4*)(ws + S2_OFF + ((size_t)b * 512 + c0) * 256);
        sp[lane]      = f4add(a0, a1);
        sp[lane + 64] = f4add(b0, b1);
    }
}

__global__ __launch_bounds__(256) void gather_kernel(
    const float* __restrict__ v0, const float* __restrict__ v1,
    const float* __restrict__ v2, const float* __restrict__ start,
    const float* __restrict__ dur, const float* __restrict__ ws,
    float* __restrict__ out)
{
    const int wave = threadIdx.x >> 6;
    const int lane = threadIdx.x & 63;
    const int half = lane >> 5;
    const int q    = lane & 31;
    const int bn   = blockIdx.x * 4 + wave;   // [0, 4096)
    const int b    = bn >> 9;
    const int pool = blockIdx.y;

    const float st = start[bn];
    const float du = dur[bn];
    float* outbase = out + (size_t)bn * 512;

    if (pool < 2) {
        const float* v  = (pool == 0) ? v0 : v1;
        const float* S  = ws + ((pool == 0) ? S0_OFF : S1_OFF);
        const int    T  = (pool == 0) ? 16384 : 8192;
        const int    NC = T / kC;
        const float  r  = (pool == 0) ? 1.0f : 0.5f;
        const int s = min((int)floorf(st * r), T - 1);
        const int e = min((int)ceilf((st + du + kEps) * r), T - 1);
        const int cnt = e - s;

        float4 a = make_float4(0, 0, 0, 0);
        if (cnt > 0) {
            const float4* vp = (const float4*)(v + (size_t)b * T * 128) + q;   // row t: vp[t*32]
            const int cs = (s + kC - 1) >> 3;
            const int ce = e >> 3;
            if (ce > cs) {
                const float4* Sp = (const float4*)(S + (size_t)b * NC * 128) + q; // chunk c: Sp[c*32]
                for (int c = cs + half; c < ce; c += 2)
                    a = f4add(a, Sp[(size_t)c * 32]);
                for (int t = s + half; t < cs * kC; t += 2)      // front edge (<=7 rows)
                    a = f4add(a, vp[(size_t)t * 32]);
                for (int t = ce * kC + half; t < e; t += 2)      // back edge (<=7 rows)
                    a = f4add(a, vp[(size_t)t * 32]);
            } else {
                for (int t = s + half; t < e; t += 2)            // short segment
                    a = f4add(a, vp[(size_t)t * 32]);
            }
        }
        // combine the two halves (each summed parity-split portions)
        a.x += __shfl_xor(a.x, 32);
        a.y += __shfl_xor(a.y, 32);
        a.z += __shfl_xor(a.z, 32);
        a.w += __shfl_xor(a.w, 32);
        float4 res = make_float4(0, 0, 0, 0);
        if (cnt > 0) {
            const float c = (float)cnt;
            res.x = a.x / c; res.y = a.y / c; res.z = a.z / c; res.w = a.w / c;
        }
        if (lane < 32)
            ((float4*)(outbase + (pool == 0 ? 0 : 128)))[q] = res;
    } else {
        const int   T  = 4096;
        const int   NC = T / kC;
        const float r  = 0.25f;
        const int s = min((int)floorf(st * r), T - 1);
        const int e = min((int)ceilf((st + du + kEps) * r), T - 1);
        const int cnt = e - s;

        float4 a0 = make_float4(0, 0, 0, 0), a1 = make_float4(0, 0, 0, 0);
        if (cnt > 0) {
            const float4* vp = (const float4*)(v2 + (size_t)b * T * 256) + lane;  // row t: vp[t*64]
            const int cs = (s + kC - 1) >> 3;
            const int ce = e >> 3;
            if (ce > cs) {
                const float4* Sp = (const float4*)(ws + S2_OFF + (size_t)b * NC * 256) + lane;
                int c = cs;
                for (; c + 2 <= ce; c += 2) {
                    a0 = f4add(a0, Sp[(size_t)c * 64]);
                    a1 = f4add(a1, Sp[(size_t)(c + 1) * 64]);
                }
                if (c < ce) a0 = f4add(a0, Sp[(size_t)c * 64]);
                for (int t = s; t < cs * kC; t++) a0 = f4add(a0, vp[(size_t)t * 64]);
                for (int t = ce * kC; t < e; t++) a1 = f4add(a1, vp[(size_t)t * 64]);
            } else {
                for (int t = s; t < e; t++) a0 = f4add(a0, vp[(size_t)t * 64]);
            }
        }
        float4 res = make_float4(0, 0, 0, 0);
        if (cnt > 0) {
            const float c = (float)cnt;
            res.x = (a0.x + a1.x) / c;
            res.y = (a0.y + a1.y) / c;
            res.z = (a0.z + a1.z) / c;
            res.w = (a0.w + a1.w) / c;
        }
        ((float4*)(outbase + 256))[lane] = res;
    }
}

extern "C" void kernel_launch(void* const* d_in, const int* in_sizes, int n_in,
                              void* d_out, int out_size, void* d_ws, size_t ws_size,
                              hipStream_t stream) {
    const float* v0    = (const float*)d_in[0];
    const float* v1    = (const float*)d_in[1];
    const float* v2    = (const float*)d_in[2];
    const float* start = (const float*)d_in[3];
    const float* dur   = (const float*)d_in[4];
    float*       out   = (float*)d_out;
    float*       ws    = (float*)d_ws;

    // Pass 1: 14336 waves (2 chunks each), 4 waves/block
    chunk_sum_kernel<<<dim3(14336 / 4), 256, 0, stream>>>(v0, v1, v2, ws);
    // Pass 2: one wave per (bn, pool)
    gather_kernel<<<dim3(kB * kN / 4, 3), 256, 0, stream>>>(v0, v1, v2, start, dur, ws, out);
}